// Round 5
// baseline (964.014 us; speedup 1.0000x reference)
//
#include <hip/hip_runtime.h>

#define N_NODES 50000
#define N_EDGES 800000
#define IN_DIM  768
#define HID_DIM 512
#define OUT_DIM 256
#define M_PAD   50048   // 391 * 128

typedef __attribute__((ext_vector_type(8))) short shortx8;        // 8 bf16 = 4 VGPRs
typedef __attribute__((ext_vector_type(4))) float floatx4;        // MFMA C/D + NT stores
typedef __attribute__((ext_vector_type(2))) unsigned int uintx2;  // NT 8B store

#define AS1 __attribute__((address_space(1)))
#define AS3 __attribute__((address_space(3)))

__device__ __forceinline__ unsigned short f2bf_rne(float f) {
    unsigned int u = __float_as_uint(f);
    unsigned int r = u + 0x7FFFu + ((u >> 16) & 1u);
    return (unsigned short)(r >> 16);
}
__device__ __forceinline__ float bf2f(unsigned short h) {
    return __uint_as_float(((unsigned int)h) << 16);
}

// ---------------------------------------------------------------------------
// Graph prep
// ---------------------------------------------------------------------------
__global__ void count_deg_kernel(const int* __restrict__ dst, int* __restrict__ deg,
                                 int n_edges) {
    int e = blockIdx.x * blockDim.x + threadIdx.x;
    if (e < n_edges) atomicAdd(&deg[dst[e]], 1);
}

#define SCAN_B 256
#define N_SCAN_BLOCKS ((N_NODES + SCAN_B - 1) / SCAN_B)   // 196

__global__ void block_sum_kernel(const int* __restrict__ deg, int* __restrict__ partials,
                                 int n) {
    __shared__ int sm[SCAN_B];
    int i = blockIdx.x * SCAN_B + threadIdx.x;
    sm[threadIdx.x] = (i < n) ? deg[i] : 0;
    __syncthreads();
    for (int off = SCAN_B / 2; off > 0; off >>= 1) {
        if (threadIdx.x < off) sm[threadIdx.x] += sm[threadIdx.x + off];
        __syncthreads();
    }
    if (threadIdx.x == 0) partials[blockIdx.x] = sm[0];
}

__global__ void scan_partials_kernel(const int* __restrict__ partials,
                                     int* __restrict__ bases, int nb) {
    __shared__ int sm[SCAN_B];
    int v = (threadIdx.x < nb) ? partials[threadIdx.x] : 0;
    sm[threadIdx.x] = v;
    __syncthreads();
    for (int off = 1; off < SCAN_B; off <<= 1) {
        int t = (threadIdx.x >= off) ? sm[threadIdx.x - off] : 0;
        __syncthreads();
        sm[threadIdx.x] += t;
        __syncthreads();
    }
    if (threadIdx.x < nb) bases[threadIdx.x] = sm[threadIdx.x] - v;   // exclusive
}

__global__ void finalize_scan_kernel(const int* __restrict__ deg, const int* __restrict__ bases,
                                     int* __restrict__ offsets, int* __restrict__ cursor,
                                     float* __restrict__ dinv, int n) {
    __shared__ int sm[SCAN_B];
    int i = blockIdx.x * SCAN_B + threadIdx.x;
    int v = (i < n) ? deg[i] : 0;
    sm[threadIdx.x] = v;
    __syncthreads();
    for (int off = 1; off < SCAN_B; off <<= 1) {
        int t = (threadIdx.x >= off) ? sm[threadIdx.x - off] : 0;
        __syncthreads();
        sm[threadIdx.x] += t;
        __syncthreads();
    }
    if (i < n) {
        int incl = bases[blockIdx.x] + sm[threadIdx.x];
        int o = incl - v;
        offsets[i] = o;
        cursor[i]  = o;
        dinv[i]    = rsqrtf((float)(v + 1));
        if (i == n - 1) offsets[n] = incl;
    }
}

__global__ void fill_csr_kernel(const int* __restrict__ src, const int* __restrict__ dst,
                                int* __restrict__ cursor, int* __restrict__ csr_src,
                                int n_edges) {
    int e = blockIdx.x * blockDim.x + threadIdx.x;
    if (e < n_edges) {
        int p = atomicAdd(&cursor[dst[e]], 1);
        csr_src[p] = src[e];
    }
}

// ---------------------------------------------------------------------------
// fp32 -> bf16 hi/lo split
// ---------------------------------------------------------------------------
__global__ void convert_split_kernel(const float* __restrict__ x,
                                     unsigned short* __restrict__ xhi,
                                     unsigned short* __restrict__ xlo,
                                     long long n4) {
    long long i = (long long)blockIdx.x * blockDim.x + threadIdx.x;
    if (i >= n4) return;
    float4 v = *reinterpret_cast<const float4*>(x + i * 4);
    ushort4 h, l;
    h.x = f2bf_rne(v.x); l.x = f2bf_rne(v.x - bf2f(h.x));
    h.y = f2bf_rne(v.y); l.y = f2bf_rne(v.y - bf2f(h.y));
    h.z = f2bf_rne(v.z); l.z = f2bf_rne(v.z - bf2f(h.z));
    h.w = f2bf_rne(v.w); l.w = f2bf_rne(v.w - bf2f(h.w));
    *reinterpret_cast<ushort4*>(xhi + i * 4) = h;
    *reinterpret_cast<ushort4*>(xlo + i * 4) = l;
}

// ---------------------------------------------------------------------------
// W [K][N] fp32 -> Wt [N][K] bf16 hi/lo
// ---------------------------------------------------------------------------
__global__ void transpose_split_kernel(const float* __restrict__ W,
                                       unsigned short* __restrict__ Whi,
                                       unsigned short* __restrict__ Wlo,
                                       int K, int N) {
    __shared__ float tile[32][33];
    int n0 = blockIdx.x * 32, k0 = blockIdx.y * 32;
    int tx = threadIdx.x, ty = threadIdx.y;
    tile[ty][tx] = W[(size_t)(k0 + ty) * N + n0 + tx];
    __syncthreads();
    float v = tile[tx][ty];
    unsigned short h = f2bf_rne(v);
    size_t o = (size_t)(n0 + ty) * K + k0 + tx;
    Whi[o] = h;
    Wlo[o] = f2bf_rne(v - bf2f(h));
}

// ---------------------------------------------------------------------------
// bf16x3 split MFMA GEMM (unchanged — verified)
// ---------------------------------------------------------------------------
#define GBK 32

__global__ __launch_bounds__(256)
void gemm_bf16x3_kernel(const unsigned short* __restrict__ Ahi,
                        const unsigned short* __restrict__ Alo,
                        const unsigned short* __restrict__ Bhi,
                        const unsigned short* __restrict__ Blo,
                        const float* __restrict__ dinv, float* __restrict__ C,
                        int M, int N, int K) {
    __shared__ __align__(16) unsigned short As[2][128][GBK];
    __shared__ __align__(16) unsigned short Bs[2][128][GBK];

    const int tid  = threadIdx.x;
    const int lane = tid & 63;
    const int wave = tid >> 6;
    const int rowBase = blockIdx.y * 128;
    const int colBase = blockIdx.x * 128;

    const unsigned short* gsrc =
        (wave == 0) ? Ahi : (wave == 1) ? Alo : (wave == 2) ? Bhi : Blo;
    unsigned short* lbase =
        (wave == 0) ? &As[0][0][0] : (wave == 1) ? &As[1][0][0]
      : (wave == 2) ? &Bs[0][0][0] : &Bs[1][0][0];
    const int rbase = (wave < 2) ? rowBase : colBase;
    const size_t laneRowOff = (size_t)(rbase + (lane >> 2)) * K + (lane & 3) * 8;

    const int m0 = (wave & 1) * 64;
    const int n0 = (wave >> 1) * 64;
    const int r16 = lane & 15;
    const int kq  = (lane >> 4) * 8;

    floatx4 acc[4][4] = {};

    for (int k0 = 0; k0 < K; k0 += GBK) {
#pragma unroll
        for (int j = 0; j < 8; j++) {
            const unsigned short* g = gsrc + laneRowOff + (size_t)(j * 16) * K + k0;
            __builtin_amdgcn_global_load_lds((const AS1 void*)g,
                                             (AS3 void*)(lbase + j * 16 * GBK),
                                             16, 0, 0);
        }
        __syncthreads();

        shortx8 ah[4], al[4], bh[4], bl[4];
#pragma unroll
        for (int i = 0; i < 4; i++) {
            ah[i] = *reinterpret_cast<const shortx8*>(&As[0][m0 + i * 16 + r16][kq]);
            al[i] = *reinterpret_cast<const shortx8*>(&As[1][m0 + i * 16 + r16][kq]);
            bh[i] = *reinterpret_cast<const shortx8*>(&Bs[0][n0 + i * 16 + r16][kq]);
            bl[i] = *reinterpret_cast<const shortx8*>(&Bs[1][n0 + i * 16 + r16][kq]);
        }
#pragma unroll
        for (int i = 0; i < 4; i++)
#pragma unroll
            for (int j = 0; j < 4; j++) {
                acc[i][j] = __builtin_amdgcn_mfma_f32_16x16x32_bf16(ah[i], bh[j], acc[i][j], 0, 0, 0);
                acc[i][j] = __builtin_amdgcn_mfma_f32_16x16x32_bf16(ah[i], bl[j], acc[i][j], 0, 0, 0);
                acc[i][j] = __builtin_amdgcn_mfma_f32_16x16x32_bf16(al[i], bh[j], acc[i][j], 0, 0, 0);
            }
        __syncthreads();
    }

#pragma unroll
    for (int i = 0; i < 4; i++) {
        int rsub = rowBase + m0 + i * 16 + (lane >> 4) * 4;
#pragma unroll
        for (int j = 0; j < 4; j++) {
            int col = colBase + n0 + j * 16 + r16;
#pragma unroll
            for (int r = 0; r < 4; r++) {
                int row = rsub + r;
                if (row < M) C[(size_t)row * N + col] = acc[i][j][r] * dinv[row];
            }
        }
    }
}

// ---------------------------------------------------------------------------
// Gather-accumulate core: LDS-staged indices, 8 outstanding float4 gathers.
// Block has F/4 threads; thread owns channels [4t, 4t+4).
// ---------------------------------------------------------------------------
template <int F>
__device__ __forceinline__ float4 gather_sum(const float* __restrict__ hs,
                                             const int* __restrict__ offsets,
                                             const int* __restrict__ csr_src,
                                             int node, int* idxs) {
    const int CHUNK = F / 4;                  // == blockDim.x
    const float* hp = hs + threadIdx.x * 4;

    float4 acc = *reinterpret_cast<const float4*>(hp + (size_t)node * F);  // self
    int beg = offsets[node], end = offsets[node + 1];
    for (int base = beg; base < end; base += CHUNK) {
        int cnt = min(CHUNK, end - base);
        __syncthreads();                       // idxs reuse guard
        if ((int)threadIdx.x < cnt) idxs[threadIdx.x] = csr_src[base + threadIdx.x];
        __syncthreads();
        int j = 0;
        for (; j + 8 <= cnt; j += 8) {
            int s0 = idxs[j + 0], s1 = idxs[j + 1], s2 = idxs[j + 2], s3 = idxs[j + 3];
            int s4 = idxs[j + 4], s5 = idxs[j + 5], s6 = idxs[j + 6], s7 = idxs[j + 7];
            float4 v0 = *reinterpret_cast<const float4*>(hp + (size_t)s0 * F);
            float4 v1 = *reinterpret_cast<const float4*>(hp + (size_t)s1 * F);
            float4 v2 = *reinterpret_cast<const float4*>(hp + (size_t)s2 * F);
            float4 v3 = *reinterpret_cast<const float4*>(hp + (size_t)s3 * F);
            float4 v4 = *reinterpret_cast<const float4*>(hp + (size_t)s4 * F);
            float4 v5 = *reinterpret_cast<const float4*>(hp + (size_t)s5 * F);
            float4 v6 = *reinterpret_cast<const float4*>(hp + (size_t)s6 * F);
            float4 v7 = *reinterpret_cast<const float4*>(hp + (size_t)s7 * F);
            acc.x += ((v0.x + v1.x) + (v2.x + v3.x)) + ((v4.x + v5.x) + (v6.x + v7.x));
            acc.y += ((v0.y + v1.y) + (v2.y + v3.y)) + ((v4.y + v5.y) + (v6.y + v7.y));
            acc.z += ((v0.z + v1.z) + (v2.z + v3.z)) + ((v4.z + v5.z) + (v6.z + v7.z));
            acc.w += ((v0.w + v1.w) + (v2.w + v3.w)) + ((v4.w + v5.w) + (v6.w + v7.w));
        }
        for (; j < cnt; j++) {
            int s = idxs[j];
            float4 v = *reinterpret_cast<const float4*>(hp + (size_t)s * F);
            acc.x += v.x; acc.y += v.y; acc.z += v.z; acc.w += v.w;
        }
    }
    return acc;
}

// ---------------------------------------------------------------------------
// Aggregation, layer 1 (F=512, 128 thr): relu + bf16 hi/lo, non-temporal out.
// ---------------------------------------------------------------------------
__global__ __launch_bounds__(128)
void aggregate1_kernel(const float* __restrict__ hs, const int* __restrict__ offsets,
                       const int* __restrict__ csr_src, const float* __restrict__ dinv,
                       const float* __restrict__ bias,
                       unsigned short* __restrict__ yhi,
                       unsigned short* __restrict__ ylo) {
    __shared__ int idxs[HID_DIM / 4];
    int node = blockIdx.x;
    int c = threadIdx.x * 4;

    float4 acc = gather_sum<HID_DIM>(hs, offsets, csr_src, node, idxs);

    float dv = dinv[node];
    float4 b = *reinterpret_cast<const float4*>(bias + c);
    float4 o = make_float4(fmaxf(acc.x * dv + b.x, 0.f), fmaxf(acc.y * dv + b.y, 0.f),
                           fmaxf(acc.z * dv + b.z, 0.f), fmaxf(acc.w * dv + b.w, 0.f));
    ushort4 h, l;
    h.x = f2bf_rne(o.x); l.x = f2bf_rne(o.x - bf2f(h.x));
    h.y = f2bf_rne(o.y); l.y = f2bf_rne(o.y - bf2f(h.y));
    h.z = f2bf_rne(o.z); l.z = f2bf_rne(o.z - bf2f(h.z));
    h.w = f2bf_rne(o.w); l.w = f2bf_rne(o.w - bf2f(h.w));
    // non-temporal: keep streaming writes out of L3 so hs stays resident
    uintx2 hw = { (unsigned)h.x | ((unsigned)h.y << 16),
                  (unsigned)h.z | ((unsigned)h.w << 16) };
    uintx2 lw = { (unsigned)l.x | ((unsigned)l.y << 16),
                  (unsigned)l.z | ((unsigned)l.w << 16) };
    __builtin_nontemporal_store(hw, reinterpret_cast<uintx2*>(yhi + (size_t)node * HID_DIM + c));
    __builtin_nontemporal_store(lw, reinterpret_cast<uintx2*>(ylo + (size_t)node * HID_DIM + c));
}

// ---------------------------------------------------------------------------
// Aggregation, layer 2 (F=256, 64 thr): fp32 out, non-temporal.
// ---------------------------------------------------------------------------
__global__ __launch_bounds__(64)
void aggregate2_kernel(const float* __restrict__ hs, const int* __restrict__ offsets,
                       const int* __restrict__ csr_src, const float* __restrict__ dinv,
                       const float* __restrict__ bias, float* __restrict__ out) {
    __shared__ int idxs[OUT_DIM / 4];
    int node = blockIdx.x;
    int c = threadIdx.x * 4;

    float4 acc = gather_sum<OUT_DIM>(hs, offsets, csr_src, node, idxs);

    float dv = dinv[node];
    float4 b = *reinterpret_cast<const float4*>(bias + c);
    floatx4 o = { acc.x * dv + b.x, acc.y * dv + b.y,
                  acc.z * dv + b.z, acc.w * dv + b.w };
    __builtin_nontemporal_store(o, reinterpret_cast<floatx4*>(out + (size_t)node * OUT_DIM + c));
}

// ---------------------------------------------------------------------------
extern "C" void kernel_launch(void* const* d_in, const int* in_sizes, int n_in,
                              void* d_out, int out_size, void* d_ws, size_t ws_size,
                              hipStream_t stream) {
    const float* x    = (const float*)d_in[0];
    const int*   edge = (const int*)d_in[1];
    const float* W1   = (const float*)d_in[2];
    const float* b1   = (const float*)d_in[3];
    const float* W2   = (const float*)d_in[4];
    const float* b2   = (const float*)d_in[5];
    float* out = (float*)d_out;

    const int* src = edge;
    const int* dst = edge + N_EDGES;

    char*  ws  = (char*)d_ws;
    size_t off = 0;
    auto alloc = [&](size_t bytes) -> void* {
        void* p = ws + off;
        off += (bytes + 255) & ~(size_t)255;
        return p;
    };
    int*   deg      = (int*)alloc((size_t)N_NODES * 4);
    float* dinv     = (float*)alloc((size_t)N_NODES * 4);
    int*   offsets  = (int*)alloc((size_t)(N_NODES + 1) * 4);
    int*   cursor   = (int*)alloc((size_t)N_NODES * 4);
    int*   csr_src  = (int*)alloc((size_t)N_EDGES * 4);
    int*   partials = (int*)alloc((size_t)N_SCAN_BLOCKS * 4);
    int*   bases    = (int*)alloc((size_t)N_SCAN_BLOCKS * 4);
    unsigned short* xhi   = (unsigned short*)alloc((size_t)M_PAD * IN_DIM * 2);
    unsigned short* xlo   = (unsigned short*)alloc((size_t)M_PAD * IN_DIM * 2);
    unsigned short* w1thi = (unsigned short*)alloc((size_t)HID_DIM * IN_DIM * 2);
    unsigned short* w1tlo = (unsigned short*)alloc((size_t)HID_DIM * IN_DIM * 2);
    unsigned short* w2thi = (unsigned short*)alloc((size_t)OUT_DIM * HID_DIM * 2);
    unsigned short* w2tlo = (unsigned short*)alloc((size_t)OUT_DIM * HID_DIM * 2);
    float* hs = (float*)alloc((size_t)N_NODES * HID_DIM * 4);

    unsigned short* y1hi = xhi;   // alias dead x regions
    unsigned short* y1lo = xlo;

    // ---- graph prep ----
    hipMemsetAsync(deg, 0, (size_t)N_NODES * 4, stream);
    count_deg_kernel<<<(N_EDGES + 255) / 256, 256, 0, stream>>>(dst, deg, N_EDGES);
    block_sum_kernel<<<N_SCAN_BLOCKS, SCAN_B, 0, stream>>>(deg, partials, N_NODES);
    scan_partials_kernel<<<1, SCAN_B, 0, stream>>>(partials, bases, N_SCAN_BLOCKS);
    finalize_scan_kernel<<<N_SCAN_BLOCKS, SCAN_B, 0, stream>>>(deg, bases, offsets, cursor,
                                                               dinv, N_NODES);
    fill_csr_kernel<<<(N_EDGES + 255) / 256, 256, 0, stream>>>(src, dst, cursor, csr_src, N_EDGES);

    // ---- precision split ----
    long long n4x = (long long)N_NODES * IN_DIM / 4;
    convert_split_kernel<<<(int)((n4x + 255) / 256), 256, 0, stream>>>(x, xhi, xlo, n4x);
    transpose_split_kernel<<<dim3(HID_DIM / 32, IN_DIM / 32), dim3(32, 32), 0, stream>>>(
        W1, w1thi, w1tlo, IN_DIM, HID_DIM);
    transpose_split_kernel<<<dim3(OUT_DIM / 32, HID_DIM / 32), dim3(32, 32), 0, stream>>>(
        W2, w2thi, w2tlo, HID_DIM, OUT_DIM);

    // ---- layer 1 ----
    gemm_bf16x3_kernel<<<dim3(HID_DIM / 128, M_PAD / 128), 256, 0, stream>>>(
        xhi, xlo, w1thi, w1tlo, dinv, hs, N_NODES, HID_DIM, IN_DIM);
    aggregate1_kernel<<<N_NODES, HID_DIM / 4, 0, stream>>>(
        hs, offsets, csr_src, dinv, b1, y1hi, y1lo);

    // ---- layer 2 ----
    gemm_bf16x3_kernel<<<dim3(OUT_DIM / 128, M_PAD / 128), 256, 0, stream>>>(
        y1hi, y1lo, w2thi, w2tlo, dinv, hs, N_NODES, OUT_DIM, HID_DIM);
    aggregate2_kernel<<<N_NODES, OUT_DIM / 4, 0, stream>>>(
        hs, offsets, csr_src, dinv, b2, out);
}

// Round 6
// 774.520 us; speedup vs baseline: 1.2447x; 1.2447x over previous
//
#include <hip/hip_runtime.h>

#define N_NODES 50000
#define N_EDGES 800000
#define IN_DIM  768
#define HID_DIM 512
#define OUT_DIM 256
#define M_PAD   50048   // 391 * 128

typedef __attribute__((ext_vector_type(8))) short shortx8;        // 8 bf16 = 16 B
typedef __attribute__((ext_vector_type(4))) short shortx4;        // 4 bf16 = 8 B
typedef __attribute__((ext_vector_type(4))) float floatx4;        // MFMA C/D + NT stores

#define AS1 __attribute__((address_space(1)))
#define AS3 __attribute__((address_space(3)))

__device__ __forceinline__ unsigned short f2bf_rne(float f) {
    unsigned int u = __float_as_uint(f);
    unsigned int r = u + 0x7FFFu + ((u >> 16) & 1u);
    return (unsigned short)(r >> 16);
}
__device__ __forceinline__ float bf2f(unsigned short h) {
    return __uint_as_float(((unsigned int)h) << 16);
}

// ---------------------------------------------------------------------------
// Graph prep
// ---------------------------------------------------------------------------
__global__ void count_deg_kernel(const int* __restrict__ dst, int* __restrict__ deg,
                                 int n_edges) {
    int e = blockIdx.x * blockDim.x + threadIdx.x;
    if (e < n_edges) atomicAdd(&deg[dst[e]], 1);
}

#define SCAN_B 256
#define N_SCAN_BLOCKS ((N_NODES + SCAN_B - 1) / SCAN_B)   // 196

__global__ void block_sum_kernel(const int* __restrict__ deg, int* __restrict__ partials,
                                 int n) {
    __shared__ int sm[SCAN_B];
    int i = blockIdx.x * SCAN_B + threadIdx.x;
    sm[threadIdx.x] = (i < n) ? deg[i] : 0;
    __syncthreads();
    for (int off = SCAN_B / 2; off > 0; off >>= 1) {
        if (threadIdx.x < off) sm[threadIdx.x] += sm[threadIdx.x + off];
        __syncthreads();
    }
    if (threadIdx.x == 0) partials[blockIdx.x] = sm[0];
}

__global__ void scan_partials_kernel(const int* __restrict__ partials,
                                     int* __restrict__ bases, int nb) {
    __shared__ int sm[SCAN_B];
    int v = (threadIdx.x < nb) ? partials[threadIdx.x] : 0;
    sm[threadIdx.x] = v;
    __syncthreads();
    for (int off = 1; off < SCAN_B; off <<= 1) {
        int t = (threadIdx.x >= off) ? sm[threadIdx.x - off] : 0;
        __syncthreads();
        sm[threadIdx.x] += t;
        __syncthreads();
    }
    if (threadIdx.x < nb) bases[threadIdx.x] = sm[threadIdx.x] - v;   // exclusive
}

__global__ void finalize_scan_kernel(const int* __restrict__ deg, const int* __restrict__ bases,
                                     int* __restrict__ offsets, int* __restrict__ cursor,
                                     float* __restrict__ dinv, int n) {
    __shared__ int sm[SCAN_B];
    int i = blockIdx.x * SCAN_B + threadIdx.x;
    int v = (i < n) ? deg[i] : 0;
    sm[threadIdx.x] = v;
    __syncthreads();
    for (int off = 1; off < SCAN_B; off <<= 1) {
        int t = (threadIdx.x >= off) ? sm[threadIdx.x - off] : 0;
        __syncthreads();
        sm[threadIdx.x] += t;
        __syncthreads();
    }
    if (i < n) {
        int incl = bases[blockIdx.x] + sm[threadIdx.x];
        int o = incl - v;
        offsets[i] = o;
        cursor[i]  = o;
        dinv[i]    = rsqrtf((float)(v + 1));
        if (i == n - 1) offsets[n] = incl;
    }
}

__global__ void fill_csr_kernel(const int* __restrict__ src, const int* __restrict__ dst,
                                int* __restrict__ cursor, int* __restrict__ csr_src,
                                int n_edges) {
    int e = blockIdx.x * blockDim.x + threadIdx.x;
    if (e < n_edges) {
        int p = atomicAdd(&cursor[dst[e]], 1);
        csr_src[p] = src[e];
    }
}

// ---------------------------------------------------------------------------
// fp32 -> bf16 hi/lo split
// ---------------------------------------------------------------------------
__global__ void convert_split_kernel(const float* __restrict__ x,
                                     unsigned short* __restrict__ xhi,
                                     unsigned short* __restrict__ xlo,
                                     long long n4) {
    long long i = (long long)blockIdx.x * blockDim.x + threadIdx.x;
    if (i >= n4) return;
    float4 v = *reinterpret_cast<const float4*>(x + i * 4);
    ushort4 h, l;
    h.x = f2bf_rne(v.x); l.x = f2bf_rne(v.x - bf2f(h.x));
    h.y = f2bf_rne(v.y); l.y = f2bf_rne(v.y - bf2f(h.y));
    h.z = f2bf_rne(v.z); l.z = f2bf_rne(v.z - bf2f(h.z));
    h.w = f2bf_rne(v.w); l.w = f2bf_rne(v.w - bf2f(h.w));
    *reinterpret_cast<ushort4*>(xhi + i * 4) = h;
    *reinterpret_cast<ushort4*>(xlo + i * 4) = l;
}

// ---------------------------------------------------------------------------
// W [K][N] fp32 -> Wt [N][K] bf16 hi/lo
// ---------------------------------------------------------------------------
__global__ void transpose_split_kernel(const float* __restrict__ W,
                                       unsigned short* __restrict__ Whi,
                                       unsigned short* __restrict__ Wlo,
                                       int K, int N) {
    __shared__ float tile[32][33];
    int n0 = blockIdx.x * 32, k0 = blockIdx.y * 32;
    int tx = threadIdx.x, ty = threadIdx.y;
    tile[ty][tx] = W[(size_t)(k0 + ty) * N + n0 + tx];
    __syncthreads();
    float v = tile[tx][ty];
    unsigned short h = f2bf_rne(v);
    size_t o = (size_t)(n0 + ty) * K + k0 + tx;
    Whi[o] = h;
    Wlo[o] = f2bf_rne(v - bf2f(h));
}

// ---------------------------------------------------------------------------
// bf16x3 split MFMA GEMM; output is now plain bf16 (feeds the gather):
//   C[r][c] = bf16( (sum_k A[r][k]*B[c][k]) * dinv[r] )
// ---------------------------------------------------------------------------
#define GBK 32

__global__ __launch_bounds__(256)
void gemm_bf16x3_kernel(const unsigned short* __restrict__ Ahi,
                        const unsigned short* __restrict__ Alo,
                        const unsigned short* __restrict__ Bhi,
                        const unsigned short* __restrict__ Blo,
                        const float* __restrict__ dinv,
                        unsigned short* __restrict__ C,
                        int M, int N, int K) {
    __shared__ __align__(16) unsigned short As[2][128][GBK];
    __shared__ __align__(16) unsigned short Bs[2][128][GBK];

    const int tid  = threadIdx.x;
    const int lane = tid & 63;
    const int wave = tid >> 6;
    const int rowBase = blockIdx.y * 128;
    const int colBase = blockIdx.x * 128;

    const unsigned short* gsrc =
        (wave == 0) ? Ahi : (wave == 1) ? Alo : (wave == 2) ? Bhi : Blo;
    unsigned short* lbase =
        (wave == 0) ? &As[0][0][0] : (wave == 1) ? &As[1][0][0]
      : (wave == 2) ? &Bs[0][0][0] : &Bs[1][0][0];
    const int rbase = (wave < 2) ? rowBase : colBase;
    const size_t laneRowOff = (size_t)(rbase + (lane >> 2)) * K + (lane & 3) * 8;

    const int m0 = (wave & 1) * 64;
    const int n0 = (wave >> 1) * 64;
    const int r16 = lane & 15;
    const int kq  = (lane >> 4) * 8;

    floatx4 acc[4][4] = {};

    for (int k0 = 0; k0 < K; k0 += GBK) {
#pragma unroll
        for (int j = 0; j < 8; j++) {
            const unsigned short* g = gsrc + laneRowOff + (size_t)(j * 16) * K + k0;
            __builtin_amdgcn_global_load_lds((const AS1 void*)g,
                                             (AS3 void*)(lbase + j * 16 * GBK),
                                             16, 0, 0);
        }
        __syncthreads();

        shortx8 ah[4], al[4], bh[4], bl[4];
#pragma unroll
        for (int i = 0; i < 4; i++) {
            ah[i] = *reinterpret_cast<const shortx8*>(&As[0][m0 + i * 16 + r16][kq]);
            al[i] = *reinterpret_cast<const shortx8*>(&As[1][m0 + i * 16 + r16][kq]);
            bh[i] = *reinterpret_cast<const shortx8*>(&Bs[0][n0 + i * 16 + r16][kq]);
            bl[i] = *reinterpret_cast<const shortx8*>(&Bs[1][n0 + i * 16 + r16][kq]);
        }
#pragma unroll
        for (int i = 0; i < 4; i++)
#pragma unroll
            for (int j = 0; j < 4; j++) {
                acc[i][j] = __builtin_amdgcn_mfma_f32_16x16x32_bf16(ah[i], bh[j], acc[i][j], 0, 0, 0);
                acc[i][j] = __builtin_amdgcn_mfma_f32_16x16x32_bf16(ah[i], bl[j], acc[i][j], 0, 0, 0);
                acc[i][j] = __builtin_amdgcn_mfma_f32_16x16x32_bf16(al[i], bh[j], acc[i][j], 0, 0, 0);
            }
        __syncthreads();
    }

#pragma unroll
    for (int i = 0; i < 4; i++) {
        int rsub = rowBase + m0 + i * 16 + (lane >> 4) * 4;
#pragma unroll
        for (int j = 0; j < 4; j++) {
            int col = colBase + n0 + j * 16 + r16;
#pragma unroll
            for (int r = 0; r < 4; r++) {
                int row = rsub + r;
                if (row < M) C[(size_t)row * N + col] = f2bf_rne(acc[i][j][r] * dinv[row]);
            }
        }
    }
}

// ---------------------------------------------------------------------------
// Aggregation, layer 1 (F=512 bf16, 64 thr, thread owns 8 channels = 16 B/row):
// out = relu((hs[self] + sum hs[nbr]) * dinv + b), written bf16 hi/lo (NT).
// ---------------------------------------------------------------------------
__global__ __launch_bounds__(64)
void aggregate1_kernel(const unsigned short* __restrict__ hs, const int* __restrict__ offsets,
                       const int* __restrict__ csr_src, const float* __restrict__ dinv,
                       const float* __restrict__ bias,
                       unsigned short* __restrict__ yhi,
                       unsigned short* __restrict__ ylo) {
    __shared__ int idxs[64];
    const int node = blockIdx.x;
    const int c = threadIdx.x * 8;
    const unsigned short* hp = hs + c;

    float acc[8];
    {
        shortx8 r = *reinterpret_cast<const shortx8*>(hp + (size_t)node * HID_DIM);
#pragma unroll
        for (int q = 0; q < 8; q++) acc[q] = bf2f((unsigned short)r[q]);
    }
    int beg = offsets[node], end = offsets[node + 1];
    for (int base = beg; base < end; base += 64) {
        int cnt = min(64, end - base);
        __syncthreads();
        if ((int)threadIdx.x < cnt) idxs[threadIdx.x] = csr_src[base + threadIdx.x];
        __syncthreads();
        int j = 0;
        for (; j + 8 <= cnt; j += 8) {
            shortx8 r0 = *reinterpret_cast<const shortx8*>(hp + (size_t)idxs[j + 0] * HID_DIM);
            shortx8 r1 = *reinterpret_cast<const shortx8*>(hp + (size_t)idxs[j + 1] * HID_DIM);
            shortx8 r2 = *reinterpret_cast<const shortx8*>(hp + (size_t)idxs[j + 2] * HID_DIM);
            shortx8 r3 = *reinterpret_cast<const shortx8*>(hp + (size_t)idxs[j + 3] * HID_DIM);
            shortx8 r4 = *reinterpret_cast<const shortx8*>(hp + (size_t)idxs[j + 4] * HID_DIM);
            shortx8 r5 = *reinterpret_cast<const shortx8*>(hp + (size_t)idxs[j + 5] * HID_DIM);
            shortx8 r6 = *reinterpret_cast<const shortx8*>(hp + (size_t)idxs[j + 6] * HID_DIM);
            shortx8 r7 = *reinterpret_cast<const shortx8*>(hp + (size_t)idxs[j + 7] * HID_DIM);
#pragma unroll
            for (int q = 0; q < 8; q++)
                acc[q] += ((bf2f((unsigned short)r0[q]) + bf2f((unsigned short)r1[q]))
                         + (bf2f((unsigned short)r2[q]) + bf2f((unsigned short)r3[q])))
                        + ((bf2f((unsigned short)r4[q]) + bf2f((unsigned short)r5[q]))
                         + (bf2f((unsigned short)r6[q]) + bf2f((unsigned short)r7[q])));
        }
        for (; j < cnt; j++) {
            shortx8 r = *reinterpret_cast<const shortx8*>(hp + (size_t)idxs[j] * HID_DIM);
#pragma unroll
            for (int q = 0; q < 8; q++) acc[q] += bf2f((unsigned short)r[q]);
        }
    }
    float dv = dinv[node];
    floatx4 b0 = *reinterpret_cast<const floatx4*>(bias + c);
    floatx4 b1 = *reinterpret_cast<const floatx4*>(bias + c + 4);
    shortx8 h8, l8;
#pragma unroll
    for (int q = 0; q < 8; q++) {
        float bq = (q < 4) ? b0[q] : b1[q - 4];
        float o = fmaxf(acc[q] * dv + bq, 0.f);
        unsigned short h = f2bf_rne(o);
        h8[q] = (short)h;
        l8[q] = (short)f2bf_rne(o - bf2f(h));
    }
    __builtin_nontemporal_store(h8, reinterpret_cast<shortx8*>(yhi + (size_t)node * HID_DIM + c));
    __builtin_nontemporal_store(l8, reinterpret_cast<shortx8*>(ylo + (size_t)node * HID_DIM + c));
}

// ---------------------------------------------------------------------------
// Aggregation, layer 2 (F=256 bf16, 64 thr, thread owns 4 channels = 8 B/row):
// fp32 out, no activation, NT store.
// ---------------------------------------------------------------------------
__global__ __launch_bounds__(64)
void aggregate2_kernel(const unsigned short* __restrict__ hs, const int* __restrict__ offsets,
                       const int* __restrict__ csr_src, const float* __restrict__ dinv,
                       const float* __restrict__ bias, float* __restrict__ out) {
    __shared__ int idxs[64];
    const int node = blockIdx.x;
    const int c = threadIdx.x * 4;
    const unsigned short* hp = hs + c;

    float acc[4];
    {
        shortx4 r = *reinterpret_cast<const shortx4*>(hp + (size_t)node * OUT_DIM);
#pragma unroll
        for (int q = 0; q < 4; q++) acc[q] = bf2f((unsigned short)r[q]);
    }
    int beg = offsets[node], end = offsets[node + 1];
    for (int base = beg; base < end; base += 64) {
        int cnt = min(64, end - base);
        __syncthreads();
        if ((int)threadIdx.x < cnt) idxs[threadIdx.x] = csr_src[base + threadIdx.x];
        __syncthreads();
        int j = 0;
        for (; j + 8 <= cnt; j += 8) {
            shortx4 r0 = *reinterpret_cast<const shortx4*>(hp + (size_t)idxs[j + 0] * OUT_DIM);
            shortx4 r1 = *reinterpret_cast<const shortx4*>(hp + (size_t)idxs[j + 1] * OUT_DIM);
            shortx4 r2 = *reinterpret_cast<const shortx4*>(hp + (size_t)idxs[j + 2] * OUT_DIM);
            shortx4 r3 = *reinterpret_cast<const shortx4*>(hp + (size_t)idxs[j + 3] * OUT_DIM);
            shortx4 r4 = *reinterpret_cast<const shortx4*>(hp + (size_t)idxs[j + 4] * OUT_DIM);
            shortx4 r5 = *reinterpret_cast<const shortx4*>(hp + (size_t)idxs[j + 5] * OUT_DIM);
            shortx4 r6 = *reinterpret_cast<const shortx4*>(hp + (size_t)idxs[j + 6] * OUT_DIM);
            shortx4 r7 = *reinterpret_cast<const shortx4*>(hp + (size_t)idxs[j + 7] * OUT_DIM);
#pragma unroll
            for (int q = 0; q < 4; q++)
                acc[q] += ((bf2f((unsigned short)r0[q]) + bf2f((unsigned short)r1[q]))
                         + (bf2f((unsigned short)r2[q]) + bf2f((unsigned short)r3[q])))
                        + ((bf2f((unsigned short)r4[q]) + bf2f((unsigned short)r5[q]))
                         + (bf2f((unsigned short)r6[q]) + bf2f((unsigned short)r7[q])));
        }
        for (; j < cnt; j++) {
            shortx4 r = *reinterpret_cast<const shortx4*>(hp + (size_t)idxs[j] * OUT_DIM);
#pragma unroll
            for (int q = 0; q < 4; q++) acc[q] += bf2f((unsigned short)r[q]);
        }
    }
    float dv = dinv[node];
    floatx4 b = *reinterpret_cast<const floatx4*>(bias + c);
    floatx4 o = { acc[0] * dv + b[0], acc[1] * dv + b[1],
                  acc[2] * dv + b[2], acc[3] * dv + b[3] };
    __builtin_nontemporal_store(o, reinterpret_cast<floatx4*>(out + (size_t)node * OUT_DIM + c));
}

// ---------------------------------------------------------------------------
extern "C" void kernel_launch(void* const* d_in, const int* in_sizes, int n_in,
                              void* d_out, int out_size, void* d_ws, size_t ws_size,
                              hipStream_t stream) {
    const float* x    = (const float*)d_in[0];
    const int*   edge = (const int*)d_in[1];
    const float* W1   = (const float*)d_in[2];
    const float* b1   = (const float*)d_in[3];
    const float* W2   = (const float*)d_in[4];
    const float* b2   = (const float*)d_in[5];
    float* out = (float*)d_out;

    const int* src = edge;
    const int* dst = edge + N_EDGES;

    char*  ws  = (char*)d_ws;
    size_t off = 0;
    auto alloc = [&](size_t bytes) -> void* {
        void* p = ws + off;
        off += (bytes + 255) & ~(size_t)255;
        return p;
    };
    int*   deg      = (int*)alloc((size_t)N_NODES * 4);
    float* dinv     = (float*)alloc((size_t)N_NODES * 4);
    int*   offsets  = (int*)alloc((size_t)(N_NODES + 1) * 4);
    int*   cursor   = (int*)alloc((size_t)N_NODES * 4);
    int*   csr_src  = (int*)alloc((size_t)N_EDGES * 4);
    int*   partials = (int*)alloc((size_t)N_SCAN_BLOCKS * 4);
    int*   bases    = (int*)alloc((size_t)N_SCAN_BLOCKS * 4);
    unsigned short* xhi   = (unsigned short*)alloc((size_t)M_PAD * IN_DIM * 2);
    unsigned short* xlo   = (unsigned short*)alloc((size_t)M_PAD * IN_DIM * 2);
    unsigned short* w1thi = (unsigned short*)alloc((size_t)HID_DIM * IN_DIM * 2);
    unsigned short* w1tlo = (unsigned short*)alloc((size_t)HID_DIM * IN_DIM * 2);
    unsigned short* w2thi = (unsigned short*)alloc((size_t)OUT_DIM * HID_DIM * 2);
    unsigned short* w2tlo = (unsigned short*)alloc((size_t)OUT_DIM * HID_DIM * 2);
    unsigned short* hs = (unsigned short*)alloc((size_t)N_NODES * HID_DIM * 2);  // bf16 pre-agg, reused L2

    unsigned short* y1hi = xhi;   // alias dead x regions
    unsigned short* y1lo = xlo;

    // ---- graph prep ----
    hipMemsetAsync(deg, 0, (size_t)N_NODES * 4, stream);
    count_deg_kernel<<<(N_EDGES + 255) / 256, 256, 0, stream>>>(dst, deg, N_EDGES);
    block_sum_kernel<<<N_SCAN_BLOCKS, SCAN_B, 0, stream>>>(deg, partials, N_NODES);
    scan_partials_kernel<<<1, SCAN_B, 0, stream>>>(partials, bases, N_SCAN_BLOCKS);
    finalize_scan_kernel<<<N_SCAN_BLOCKS, SCAN_B, 0, stream>>>(deg, bases, offsets, cursor,
                                                               dinv, N_NODES);
    fill_csr_kernel<<<(N_EDGES + 255) / 256, 256, 0, stream>>>(src, dst, cursor, csr_src, N_EDGES);

    // ---- precision split ----
    long long n4x = (long long)N_NODES * IN_DIM / 4;
    convert_split_kernel<<<(int)((n4x + 255) / 256), 256, 0, stream>>>(x, xhi, xlo, n4x);
    transpose_split_kernel<<<dim3(HID_DIM / 32, IN_DIM / 32), dim3(32, 32), 0, stream>>>(
        W1, w1thi, w1tlo, IN_DIM, HID_DIM);
    transpose_split_kernel<<<dim3(OUT_DIM / 32, HID_DIM / 32), dim3(32, 32), 0, stream>>>(
        W2, w2thi, w2tlo, HID_DIM, OUT_DIM);

    // ---- layer 1 ----
    gemm_bf16x3_kernel<<<dim3(HID_DIM / 128, M_PAD / 128), 256, 0, stream>>>(
        xhi, xlo, w1thi, w1tlo, dinv, hs, N_NODES, HID_DIM, IN_DIM);
    aggregate1_kernel<<<N_NODES, 64, 0, stream>>>(
        hs, offsets, csr_src, dinv, b1, y1hi, y1lo);

    // ---- layer 2 ----
    gemm_bf16x3_kernel<<<dim3(OUT_DIM / 128, M_PAD / 128), 256, 0, stream>>>(
        y1hi, y1lo, w2thi, w2tlo, dinv, hs, N_NODES, OUT_DIM, HID_DIM);
    aggregate2_kernel<<<N_NODES, 64, 0, stream>>>(
        hs, offsets, csr_src, dinv, b2, out);
}